// Round 10
// baseline (6653.920 us; speedup 1.0000x reference)
//
#include <hip/hip_runtime.h>
#include <hip/hip_bf16.h>
#include <cstdint>
#include <cstddef>

// ---------------- model dims ----------------
#define B_SZ    2048
#define H_SZ    512
#define G4      2048      // 4*H
#define TSTEPS  21
#define MAXLEN  1000
#define KIH     1024      // padded input-K (layer1 dense input: 2H=1024)
#define KCAT    1536      // KIH + H_SZ
#define NCLS    10
#define CAP     128       // CSR slots per (t,b); mean 47.6, sigma 6.7 -> 12 sigma

// ---------------- GEMM tile ----------------
#define BM 128
#define BN 128
#define BK 32
#define NIT  (KCAT / BK)  // 48
#define LDSK 40           // padded LDS K-stride (elements); 80 B keeps 16B alignment
#define GPAD 33           // gates chunk stride (floats)

typedef short bf16x8 __attribute__((ext_vector_type(8)));            // 8 bf16 (4 VGPRs)
typedef float f32x4  __attribute__((ext_vector_type(4)));
typedef unsigned short ushort8 __attribute__((ext_vector_type(8)));  // 16B vector

__device__ __forceinline__ unsigned short f2bf(float f) {
  __hip_bfloat16 h = __float2bfloat16(f);
  unsigned short u;
  __builtin_memcpy(&u, &h, sizeof(u));
  return u;
}
__device__ __forceinline__ float bf2f(unsigned short u) {
  __hip_bfloat16 h;
  __builtin_memcpy(&h, &u, sizeof(h));
  return __bfloat162float(h);
}

__device__ __forceinline__ float sigmoidf_(float x) {
  x = fminf(fmaxf(x, -30.f), 30.f);
  return 1.f / (1.f + __expf(-x));
}
__device__ __forceinline__ float tanhf_(float x) {
  float xc = fminf(fmaxf(x, -15.f), 15.f);
  float e = __expf(2.f * xc);
  return (e - 1.f) / (e + 1.f);
}

// gate-row permutation: p = 4*j + type  <->  orig row r = type*512 + j (i,f,g,o)
__device__ __forceinline__ int rbase_of(int p) { return (p & 3) * H_SZ + (p >> 2); }

// ============================================================
// prep: layer-1 B = [W_ih1 | W_hh1] permuted; hi full, lo recurrent-only
// ============================================================
__global__ void prep_w1_kernel(const float* __restrict__ w_ih1,
                               const float* __restrict__ w_hh1,
                               unsigned short* __restrict__ Bhi1,   // [2,G4,KCAT]
                               unsigned short* __restrict__ Blo1) { // [2,G4,512]
  size_t idx = (size_t)blockIdx.x * blockDim.x + threadIdx.x;
  const size_t total = (size_t)2 * G4 * KCAT;
  if (idx >= total) return;
  int cc = (int)(idx % KCAT);
  size_t rowidx = idx / KCAT;
  int p  = (int)(rowidx % G4);
  int dd = (int)(rowidx / G4);
  size_t rb = (size_t)dd * G4 + rbase_of(p);

  float w1 = (cc < KIH) ? w_ih1[rb * KIH + cc] : w_hh1[rb * H_SZ + (cc - KIH)];
  unsigned short h1 = f2bf(w1);
  Bhi1[idx] = h1;
  if (cc >= KIH)
    Blo1[((size_t)dd * G4 + p) * H_SZ + (cc - KIH)] = f2bf(w1 - bf2f(h1));
}

// ============================================================
// prep: layer-0 recurrent B (hi+lo), [2,G4,512]
// ============================================================
__global__ void prep_w0_kernel(const float* __restrict__ w_hh0,
                               unsigned short* __restrict__ Br0hi,
                               unsigned short* __restrict__ Br0lo) {
  size_t idx = (size_t)blockIdx.x * blockDim.x + threadIdx.x;
  const size_t total = (size_t)2 * G4 * H_SZ;
  if (idx >= total) return;
  int k  = (int)(idx % H_SZ);
  size_t rowidx = idx / H_SZ;
  int p  = (int)(rowidx % G4);
  int dd = (int)(rowidx / G4);
  size_t rb = (size_t)dd * G4 + rbase_of(p);
  float w = w_hh0[rb * H_SZ + k];
  unsigned short h = f2bf(w);
  Br0hi[idx] = h;
  Br0lo[idx] = f2bf(w - bf2f(h));
}

// ============================================================
// prep: transposed layer-0 input weights Wt0[d][k][p] (bf16 hi), coalesced writes
// ============================================================
__global__ void prep_wt0_kernel(const float* __restrict__ w_ih0,
                                unsigned short* __restrict__ Wt0) { // [2,KIH,G4]
  size_t idx = (size_t)blockIdx.x * blockDim.x + threadIdx.x;
  const size_t total = (size_t)2 * KIH * G4;
  if (idx >= total) return;
  int p  = (int)(idx % G4);
  size_t rem = idx / G4;
  int k  = (int)(rem % KIH);
  int dd = (int)(rem / KIH);
  size_t rb = (size_t)dd * G4 + rbase_of(p);
  float v = (k < MAXLEN) ? w_ih0[rb * MAXLEN + k] : 0.f;
  Wt0[idx] = f2bf(v);
}

__global__ void prep_b_kernel(const float* __restrict__ b_ih0,
                              const float* __restrict__ b_hh0,
                              const float* __restrict__ b_ih1,
                              const float* __restrict__ b_hh1,
                              float* __restrict__ bias0,
                              float* __restrict__ bias1) {
  int idx = blockIdx.x * blockDim.x + threadIdx.x;   // 0 .. 2*G4-1
  if (idx >= 2 * G4) return;
  int p  = idx % G4;
  int dd = idx / G4;
  int src = dd * G4 + rbase_of(p);
  bias0[idx] = b_ih0[src] + b_hh0[src];
  bias1[idx] = b_ih1[src] + b_hh1[src];
}

// ============================================================
// prep: CSR of one-hot matches. lst[t][b][slot] = position i with x[b,i]==t.
// ============================================================
__global__ void prep_csr_kernel(const int* __restrict__ x,
                                unsigned short* __restrict__ lst,  // [21,B,CAP]
                                int* __restrict__ cnt) {           // [21,B]
  __shared__ int lc[TSTEPS];
  const int b = blockIdx.x;
  const int tid = threadIdx.x;
  if (tid < TSTEPS) lc[tid] = 0;
  __syncthreads();
  for (int i = tid; i < MAXLEN; i += 256) {
    int t = x[(size_t)b * MAXLEN + i];
    int slot = atomicAdd(&lc[t], 1);
    if (slot < CAP) lst[((size_t)t * B_SZ + b) * CAP + slot] = (unsigned short)i;
  }
  __syncthreads();
  if (tid < TSTEPS) cnt[tid * B_SZ + b] = (lc[tid] < CAP) ? lc[tid] : CAP;
}

// ============================================================
// per-step layer-0 input projection via CSR gather-sum (one-hot GEMM, 21x less
// work than dense MFMA): gx0[d][b][p] = sum_{pos in csr[tcur_d][b]} Wt0[d][pos][p]
// ============================================================
__global__ __launch_bounds__(256)
void scatter_gx0_kernel(const unsigned short* __restrict__ Wt0,  // [2,KIH,G4]
                        const unsigned short* __restrict__ lst,
                        const int* __restrict__ cnt,
                        float* __restrict__ gx0,                 // [2,B,G4]
                        int step) {
  const int gb = blockIdx.x * 128;       // 16 gate-chunks
  const int bb = blockIdx.y * 128;       // 16 b-blocks
  const int d  = blockIdx.z;
  const int tcur = d ? (TSTEPS - 1 - step) : step;
  const int lane = threadIdx.x & 63;
  const int w    = threadIdx.x >> 6;     // 4 waves
  const int g = gb + lane * 2;
  const unsigned short* Wd = Wt0 + (size_t)d * KIH * G4;

  for (int r = w; r < 128; r += 4) {
    int b = bb + r;
    int n = cnt[tcur * B_SZ + b];
    const unsigned short* lp = lst + ((size_t)tcur * B_SZ + b) * CAP;
    float a0 = 0.f, a1 = 0.f;
    int ii = 0;
    for (; ii + 4 <= n; ii += 4) {
      int p0 = lp[ii], p1 = lp[ii + 1], p2 = lp[ii + 2], p3 = lp[ii + 3];
      unsigned int u0 = *(const unsigned int*)(Wd + (size_t)p0 * G4 + g);
      unsigned int u1 = *(const unsigned int*)(Wd + (size_t)p1 * G4 + g);
      unsigned int u2 = *(const unsigned int*)(Wd + (size_t)p2 * G4 + g);
      unsigned int u3 = *(const unsigned int*)(Wd + (size_t)p3 * G4 + g);
      a0 += bf2f((unsigned short)(u0 & 0xffff)) + bf2f((unsigned short)(u1 & 0xffff))
          + bf2f((unsigned short)(u2 & 0xffff)) + bf2f((unsigned short)(u3 & 0xffff));
      a1 += bf2f((unsigned short)(u0 >> 16)) + bf2f((unsigned short)(u1 >> 16))
          + bf2f((unsigned short)(u2 >> 16)) + bf2f((unsigned short)(u3 >> 16));
    }
    for (; ii < n; ++ii) {
      unsigned int u = *(const unsigned int*)(Wd + (size_t)lp[ii] * G4 + g);
      a0 += bf2f((unsigned short)(u & 0xffff));
      a1 += bf2f((unsigned short)(u >> 16));
    }
    *(float2*)(gx0 + ((size_t)d * B_SZ + b) * G4 + g) = make_float2(a0, a1);
  }
}

// ============================================================
// one recurrent step. 1D grid of 512 blocks, XCD-swizzled decode.
// LAYER 0: K-loop = recurrent only (16 iters, k in [KIH,KCAT)); input projection
//          comes in via gx0 (added in the cell epilogue).
// LAYER 1: full 48 iters (dense seq input K=1024 + recurrent 512 hi+lo).
// Double-buffered LDS, ONE barrier per K-iter; register prefetch depth 2.
// ============================================================
template <int LAYER>
__global__ __launch_bounds__(512, 4)
void step_kernel(const unsigned short* __restrict__ seq_in,   // [T,B,2H] (L1)
                 const unsigned short* __restrict__ Bhi,      // L0:[2,G4,512] L1:[2,G4,KCAT]
                 const unsigned short* __restrict__ Blo,      // [2,G4,512]
                 const float* __restrict__ bias,              // [2,G4] f32
                 const unsigned short* __restrict__ h_in,     // [2,B,H] bf16
                 unsigned short* __restrict__ h_out,          // [2,B,H] bf16
                 float* __restrict__ c_st,                    // [2,B,H] f32
                 unsigned short* __restrict__ seq_out,        // [T,B,2H]   (L0)
                 const float* __restrict__ gx0,               // [2,B,G4]   (L0)
                 float* __restrict__ zacc,                    // [B,2H] f32 (L1)
                 const float* __restrict__ emb_w,             // [21] f32   (L1)
                 int step) {
  constexpr int KSTART = (LAYER == 0) ? (KIH / BK) : 0;   // 32 or 0
  constexpr int BHSTR  = (LAYER == 0) ? H_SZ : KCAT;      // Bhi row stride
  constexpr int BHOFF  = (LAYER == 0) ? KIH : 0;          // Bhi k offset

  __shared__ union {
    struct {
      unsigned short A[BM * LDSK];    // 10 KB
      unsigned short Bh[BN * LDSK];   // 10 KB
      unsigned short Bl[BN * LDSK];   // 10 KB
    } t[2];                           // 60 KB double buffer
    float gc[BM * GPAD];              // 16.9 KB gates chunk
  } sm;

  const int tid  = threadIdx.x;
  const int lane = tid & 63;
  const int wave = tid >> 6;          // 0..7
  const int wr   = wave >> 1;         // 0..3  (M: wr*32 + mt*16)
  const int wc   = wave & 1;          // 0..1  (N: wc*64 + nt*16)
  const int q    = lane >> 4;
  const int r16  = lane & 15;

  // ---- XCD-swizzled block decode: bid = slot<<3 | xcd ----
  const int bid  = blockIdx.x;        // 0..511
  const int xcd  = bid & 7;
  const int slot = bid >> 3;          // 0..63 = d*32 + mb*2 + nsub
  const int nb   = xcd * 2 + (slot & 1);
  const int mb   = (slot >> 1) & 15;
  const int d    = slot >> 5;

  const int tcur = d ? (TSTEPS - 1 - step) : step;
  const int n0   = nb * BN;
  const int m0   = mb * BM;

  const unsigned short* Bh_mat = Bhi + (size_t)d * G4 * BHSTR;
  const unsigned short* Bl_mat = Blo + (size_t)d * G4 * H_SZ;

  float bval[4];
#pragma unroll
  for (int nt = 0; nt < 4; ++nt)
    bval[nt] = bias[d * G4 + n0 + wc * 64 + nt * 16 + r16];

  f32x4 acc[2][4];
#pragma unroll
  for (int mt = 0; mt < 2; ++mt)
#pragma unroll
    for (int nt = 0; nt < 4; ++nt) {
      f32x4 z = {0.f, 0.f, 0.f, 0.f};
      acc[mt][nt] = z;
    }

  const int rstg = tid >> 2;            // tile row 0..127
  const int ostg = (tid & 3) * 8;       // k offset 0/8/16/24

  // ---- prefetch payload register sets (depth 2) ----
  ushort8 pbh[2], pbl[2], pva[2];

  auto load_iter = [&](int kt, int s) {
    const int k0 = kt * BK;
    pbh[s] = *(const ushort8*)(Bh_mat + (size_t)(n0 + rstg) * BHSTR + (k0 - BHOFF) + ostg);
    if (LAYER == 0 || k0 >= KIH) {
      pbl[s] = *(const ushort8*)(Bl_mat + (size_t)(n0 + rstg) * H_SZ + (k0 - KIH) + ostg);
      pva[s] = *(const ushort8*)(h_in + (size_t)d * B_SZ * H_SZ
                                 + (size_t)(m0 + rstg) * H_SZ + (k0 - KIH) + ostg);
    } else {
      pva[s] = *(const ushort8*)(seq_in + (size_t)tcur * B_SZ * (2 * H_SZ)
                                 + (size_t)(m0 + rstg) * (2 * H_SZ) + k0 + ostg);
    }
  };

  auto body = [&](int kt, int s) {
    const int k0 = kt * BK;
    const bool useLo = (LAYER == 0) || (k0 >= KIH);

    *(ushort8*)(sm.t[s].A + rstg * LDSK + ostg) = pva[s];
    *(ushort8*)(sm.t[s].Bh + rstg * LDSK + ostg) = pbh[s];
    if (useLo)
      *(ushort8*)(sm.t[s].Bl + rstg * LDSK + ostg) = pbl[s];
    __syncthreads();   // the ONLY barrier this iteration (dbuf makes it safe)

    if (kt + 2 < NIT) load_iter(kt + 2, s);

    // A/B fragment: m/n = lane&15, k = (lane>>4)*8 + j   [m89/m91 verified]
    bf16x8 af[2], bh[4];
#pragma unroll
    for (int mt = 0; mt < 2; ++mt)
      af[mt] = *(const bf16x8*)(sm.t[s].A + (wr * 32 + mt * 16 + r16) * LDSK + q * 8);
#pragma unroll
    for (int nt = 0; nt < 4; ++nt)
      bh[nt] = *(const bf16x8*)(sm.t[s].Bh + (wc * 64 + nt * 16 + r16) * LDSK + q * 8);
#pragma unroll
    for (int mt = 0; mt < 2; ++mt)
#pragma unroll
      for (int nt = 0; nt < 4; ++nt)
        acc[mt][nt] = __builtin_amdgcn_mfma_f32_16x16x32_bf16(af[mt], bh[nt], acc[mt][nt], 0, 0, 0);
    if (useLo) {
      bf16x8 bl[4];
#pragma unroll
      for (int nt = 0; nt < 4; ++nt)
        bl[nt] = *(const bf16x8*)(sm.t[s].Bl + (wc * 64 + nt * 16 + r16) * LDSK + q * 8);
#pragma unroll
      for (int mt = 0; mt < 2; ++mt)
#pragma unroll
        for (int nt = 0; nt < 4; ++nt)
          acc[mt][nt] = __builtin_amdgcn_mfma_f32_16x16x32_bf16(af[mt], bl[nt], acc[mt][nt], 0, 0, 0);
    }
  };

  load_iter(KSTART, 0);
  load_iter(KSTART + 1, 1);
  for (int kt = KSTART; kt < NIT; kt += 2) {   // iter count even for both layers
    body(kt, 0);
    body(kt + 1, 1);
  }
  __syncthreads();   // all MFMA LDS reads done before gates scratch overwrite

  // ---- epilogue: 4 chunks of 32 gate-cols through 128x33 LDS scratch ----
  // C/D layout: col = lane&15, row = (lane>>4)*4 + reg   [m89/m91 verified]
  const int jbase = nb * 32;
  const float ew = (LAYER == 1) ? emb_w[tcur] : 0.f;

#pragma unroll
  for (int cc2 = 0; cc2 < 4; ++cc2) {
    if (wc == (cc2 >> 1)) {
      const int ntb = (cc2 & 1) * 2;
#pragma unroll
      for (int nti = 0; nti < 2; ++nti) {
        const int nt = ntb + nti;
#pragma unroll
        for (int mt = 0; mt < 2; ++mt)
#pragma unroll
          for (int r = 0; r < 4; ++r) {
            int ml = wr * 32 + mt * 16 + q * 4 + r;
            int nl = nti * 16 + r16;
            sm.gc[ml * GPAD + nl] = acc[mt][nt][r] + bval[nt];
          }
      }
    }
    __syncthreads();

#pragma unroll
    for (int it = 0; it < 2; ++it) {
      int cell = it * 512 + tid;
      int rl = cell >> 3;        // row 0..127
      int jq = cell & 7;         // col-quad within chunk
      int b = m0 + rl;
      int j = jbase + cc2 * 8 + jq;
      float4 g = *(const float4*)(&sm.gc[rl * GPAD + jq * 4]);
      if (LAYER == 0) {
        // add hoisted input projection (permuted gate space: p = 4j..4j+3)
        const float4 gx = *(const float4*)(gx0 + ((size_t)d * B_SZ + b) * G4 + (size_t)j * 4);
        g.x += gx.x; g.y += gx.y; g.z += gx.z; g.w += gx.w;
      }
      float si = sigmoidf_(g.x);
      float sf = sigmoidf_(g.y);
      float tg = tanhf_(g.z);
      float so = sigmoidf_(g.w);
      size_t cidx = ((size_t)d * B_SZ + b) * H_SZ + j;
      float cn = sf * c_st[cidx] + si * tg;
      float hv = so * tanhf_(cn);
      c_st[cidx] = cn;
      h_out[cidx] = f2bf(hv);
      if (LAYER == 0) {
        seq_out[((size_t)tcur * B_SZ + b) * (2 * H_SZ) + d * H_SZ + j] = f2bf(hv);
      } else {
        zacc[(size_t)b * (2 * H_SZ) + d * H_SZ + j] += ew * hv;
      }
    }
    __syncthreads();
  }
}

// ============================================================
// final: z[b,:] = zacc[b,:] + emb_b ; out = z @ fc_w^T + fc_b   (all f32)
// ============================================================
__global__ __launch_bounds__(256)
void final_kernel(const float* __restrict__ zacc,    // [B, 2H] f32
                  const float* __restrict__ emb_b,   // [1]
                  const float* __restrict__ fc_w,    // [10, 2H]
                  const float* __restrict__ fc_b,    // [10]
                  float* __restrict__ out) {         // [B, 10] f32
  const int b = blockIdx.x;
  const int tid = threadIdx.x;
  const int c0 = tid * 4;

  const float zb = emb_b[0];
  const float4 z4 = *(const float4*)(zacc + (size_t)b * (2 * H_SZ) + c0);
  float z0 = z4.x + zb, z1 = z4.y + zb, z2 = z4.z + zb, z3 = z4.w + zb;

  float part[NCLS];
#pragma unroll
  for (int nc = 0; nc < NCLS; ++nc) {
    const float4 f = *(const float4*)(fc_w + (size_t)nc * (2 * H_SZ) + c0);
    part[nc] = z0 * f.x + z1 * f.y + z2 * f.z + z3 * f.w;
  }
#pragma unroll
  for (int nc = 0; nc < NCLS; ++nc)
#pragma unroll
    for (int off2 = 32; off2 > 0; off2 >>= 1)
      part[nc] += __shfl_down(part[nc], off2);

  __shared__ float red[4][NCLS];
  if ((tid & 63) == 0) {
#pragma unroll
    for (int nc = 0; nc < NCLS; ++nc) red[tid >> 6][nc] = part[nc];
  }
  __syncthreads();
  if (tid < NCLS) {
    float s = red[0][tid] + red[1][tid] + red[2][tid] + red[3][tid] + fc_b[tid];
    out[b * NCLS + tid] = s;
  }
}

// ============================================================
extern "C" void kernel_launch(void* const* d_in, const int* in_sizes, int n_in,
                              void* d_out, int out_size, void* d_ws, size_t ws_size,
                              hipStream_t stream) {
  (void)in_sizes; (void)n_in; (void)out_size; (void)ws_size;

  const int*   x     = (const int*)d_in[0];
  const float* w_ih0 = (const float*)d_in[1];
  const float* w_hh0 = (const float*)d_in[2];
  const float* b_ih0 = (const float*)d_in[3];
  const float* b_hh0 = (const float*)d_in[4];
  const float* w_ih1 = (const float*)d_in[5];
  const float* w_hh1 = (const float*)d_in[6];
  const float* b_ih1 = (const float*)d_in[7];
  const float* b_hh1 = (const float*)d_in[8];
  const float* emb_w = (const float*)d_in[9];
  const float* emb_b = (const float*)d_in[10];
  const float* fc_w  = (const float*)d_in[11];
  const float* fc_b  = (const float*)d_in[12];

  // -------- workspace layout (~183 MB) --------
  char* ws = (char*)d_ws;
  size_t off = 0;
  auto alloc = [&](size_t bytes) -> void* {
    void* p = ws + off;
    off += (bytes + 255) & ~(size_t)255;
    return p;
  };
  const size_t bhi1_b = (size_t)2 * G4 * KCAT * 2;              // 12.6 MB
  const size_t brec_b = (size_t)2 * G4 * H_SZ * 2;              // 4.2 MB each
  const size_t wt0_b  = (size_t)2 * KIH * G4 * 2;               // 8.4 MB
  const size_t h_b    = (size_t)2 * B_SZ * H_SZ * 2;            // 4.2 MB
  const size_t c_b    = (size_t)2 * B_SZ * H_SZ * 4;            // 8.4 MB
  const size_t seq_b  = (size_t)TSTEPS * B_SZ * (2 * H_SZ) * 2; // 88 MB
  const size_t gx0_b  = (size_t)2 * B_SZ * G4 * 4;              // 33.6 MB
  const size_t z_b    = (size_t)B_SZ * (2 * H_SZ) * 4;          // 8.4 MB (aliases gx0)
  const size_t lst_b  = (size_t)TSTEPS * B_SZ * CAP * 2;        // 11.0 MB
  const size_t cnt_b  = (size_t)TSTEPS * B_SZ * 4;              // 0.17 MB

  unsigned short* Bhi1  = (unsigned short*)alloc(bhi1_b);
  unsigned short* Blo1  = (unsigned short*)alloc(brec_b);
  unsigned short* Br0hi = (unsigned short*)alloc(brec_b);
  unsigned short* Br0lo = (unsigned short*)alloc(brec_b);
  unsigned short* Wt0   = (unsigned short*)alloc(wt0_b);
  float*          bias0 = (float*)alloc((size_t)2 * G4 * 4);
  float*          bias1 = (float*)alloc((size_t)2 * G4 * 4);
  unsigned short* hA    = (unsigned short*)alloc(h_b);
  unsigned short* hB    = (unsigned short*)alloc(h_b);
  float*          cst   = (float*)alloc(c_b);
  float*          gx0   = (float*)alloc(gx0_b);
  float*          zacc  = gx0;                       // layer-1 only; aliases gx0
  unsigned short* lst   = (unsigned short*)alloc(lst_b);
  int*            cnt   = (int*)alloc(cnt_b);
  unsigned short* seq0  = (unsigned short*)alloc(seq_b);

  // -------- prep --------
  {
    size_t t1 = (size_t)2 * G4 * KCAT;
    prep_w1_kernel<<<(int)((t1 + 255) / 256), 256, 0, stream>>>(w_ih1, w_hh1, Bhi1, Blo1);
    size_t t0 = (size_t)2 * G4 * H_SZ;
    prep_w0_kernel<<<(int)((t0 + 255) / 256), 256, 0, stream>>>(w_hh0, Br0hi, Br0lo);
    size_t tw = (size_t)2 * KIH * G4;
    prep_wt0_kernel<<<(int)((tw + 255) / 256), 256, 0, stream>>>(w_ih0, Wt0);
    prep_b_kernel<<<16, 256, 0, stream>>>(b_ih0, b_hh0, b_ih1, b_hh1, bias0, bias1);
    prep_csr_kernel<<<B_SZ, 256, 0, stream>>>(x, lst, cnt);
  }

  const int nblocks = 512;   // 1D, XCD-swizzled decode inside kernel
  dim3 sgrid(16, 16, 2);     // scatter: gate-chunks x b-blocks x dirs

  // -------- layer 0 (recurrent K=512 only; input proj via scatter) --------
  hipMemsetAsync(hA, 0, h_b, stream);
  hipMemsetAsync(cst, 0, c_b, stream);
  for (int s = 0; s < TSTEPS; ++s) {
    scatter_gx0_kernel<<<sgrid, 256, 0, stream>>>(Wt0, lst, cnt, gx0, s);
    const unsigned short* hin  = (s & 1) ? hB : hA;
    unsigned short*       hout = (s & 1) ? hA : hB;
    step_kernel<0><<<nblocks, 512, 0, stream>>>(nullptr, Br0hi, Br0lo, bias0, hin, hout, cst,
                                                seq0, gx0, nullptr, nullptr, s);
  }

  // -------- layer 1 (emb contraction fused into epilogue) --------
  hipMemsetAsync(hA, 0, h_b, stream);
  hipMemsetAsync(cst, 0, c_b, stream);
  hipMemsetAsync(zacc, 0, z_b, stream);   // gx0 no longer needed
  for (int s = 0; s < TSTEPS; ++s) {
    const unsigned short* hin  = (s & 1) ? hB : hA;
    unsigned short*       hout = (s & 1) ? hA : hB;
    step_kernel<1><<<nblocks, 512, 0, stream>>>(seq0, Bhi1, Blo1, bias1, hin, hout, cst,
                                                nullptr, nullptr, zacc, emb_w, s);
  }

  // -------- fc --------
  final_kernel<<<B_SZ, 256, 0, stream>>>(zacc, emb_b, fc_w, fc_b, (float*)d_out);
}

// Round 11
// 3843.457 us; speedup vs baseline: 1.7312x; 1.7312x over previous
//
#include <hip/hip_runtime.h>
#include <hip/hip_bf16.h>
#include <cstdint>
#include <cstddef>

// ---------------- model dims ----------------
#define B_SZ    2048
#define H_SZ    512
#define G4      2048      // 4*H
#define TSTEPS  21
#define MAXLEN  1000
#define KIN     1024      // input-K (L0 one-hot padded 1000->1024; L1 2H=1024)
#define NCLS    10

// ---------------- tiles ----------------
#define BM    128
#define BN    128
#define BKS   32          // step-role K-tile (recurrent K=512 -> 16 iters)
#define LDSKS 40          // step LDS K-stride (80 B, 16B-aligned)
#define NITS  16
#define BKG   64          // gx-role K-tile (K=1024 -> 16 iters, balanced with step)
#define LDSKG 72          // gx LDS K-stride (144 B, 16B-aligned)
#define NITG  16
#define GPAD  33
#define SMEM_BYTES 36864  // max(step 30720/gc 16896, gx 36864) -> 4 blocks/CU

typedef short bf16x8 __attribute__((ext_vector_type(8)));
typedef float f32x4  __attribute__((ext_vector_type(4)));
typedef unsigned short ushort8 __attribute__((ext_vector_type(8)));

__device__ __forceinline__ unsigned short f2bf(float f) {
  __hip_bfloat16 h = __float2bfloat16(f);
  unsigned short u; __builtin_memcpy(&u, &h, sizeof(u)); return u;
}
__device__ __forceinline__ float bf2f(unsigned short u) {
  __hip_bfloat16 h; __builtin_memcpy(&h, &u, sizeof(h)); return __bfloat162float(h);
}
__device__ __forceinline__ float sigmoidf_(float x) {
  x = fminf(fmaxf(x, -30.f), 30.f);
  return 1.f / (1.f + __expf(-x));
}
__device__ __forceinline__ float tanhf_(float x) {
  float xc = fminf(fmaxf(x, -15.f), 15.f);
  float e = __expf(2.f * xc);
  return (e - 1.f) / (e + 1.f);
}
// gate permutation p = 4*j + type  <->  orig row type*512 + j (i,f,g,o)
__device__ __forceinline__ int rbase_of(int p) { return (p & 3) * H_SZ + (p >> 2); }

// ============================================================ prep kernels
__global__ void prep_rec_kernel(const float* __restrict__ w_hh,
                                unsigned short* __restrict__ Bhi,
                                unsigned short* __restrict__ Blo) {
  size_t idx = (size_t)blockIdx.x * blockDim.x + threadIdx.x;
  const size_t total = (size_t)2 * G4 * H_SZ;
  if (idx >= total) return;
  int k  = (int)(idx % H_SZ);
  size_t rowidx = idx / H_SZ;
  int p  = (int)(rowidx % G4);
  int dd = (int)(rowidx / G4);
  float w = w_hh[((size_t)dd * G4 + rbase_of(p)) * H_SZ + k];
  unsigned short h = f2bf(w);
  Bhi[idx] = h;
  Blo[idx] = f2bf(w - bf2f(h));
}

__global__ void prep_in0_kernel(const float* __restrict__ w_ih0,
                                unsigned short* __restrict__ Bin0) {  // [2,G4,KIN]
  size_t idx = (size_t)blockIdx.x * blockDim.x + threadIdx.x;
  const size_t total = (size_t)2 * G4 * KIN;
  if (idx >= total) return;
  int k  = (int)(idx % KIN);
  size_t rowidx = idx / KIN;
  int p  = (int)(rowidx % G4);
  int dd = (int)(rowidx / G4);
  float v = (k < MAXLEN) ? w_ih0[((size_t)dd * G4 + rbase_of(p)) * MAXLEN + k] : 0.f;
  Bin0[idx] = f2bf(v);
}

__global__ void prep_in1_kernel(const float* __restrict__ w_ih1,
                                unsigned short* __restrict__ Bin1) {  // [2,G4,KIN]
  size_t idx = (size_t)blockIdx.x * blockDim.x + threadIdx.x;
  const size_t total = (size_t)2 * G4 * KIN;
  if (idx >= total) return;
  int k  = (int)(idx % KIN);
  size_t rowidx = idx / KIN;
  int p  = (int)(rowidx % G4);
  int dd = (int)(rowidx / G4);
  Bin1[idx] = f2bf(w_ih1[((size_t)dd * G4 + rbase_of(p)) * KIN + k]);
}

__global__ void prep_b_kernel(const float* __restrict__ b_ih0,
                              const float* __restrict__ b_hh0,
                              const float* __restrict__ b_ih1,
                              const float* __restrict__ b_hh1,
                              float* __restrict__ bias0,
                              float* __restrict__ bias1) {
  int idx = blockIdx.x * blockDim.x + threadIdx.x;
  if (idx >= 2 * G4) return;
  int p  = idx % G4;
  int dd = idx / G4;
  int src = dd * G4 + rbase_of(p);
  bias0[idx] = b_ih0[src] + b_hh0[src];
  bias1[idx] = b_ih1[src] + b_hh1[src];
}

// one-hot bitmasks: bits[t][b][w] bit j set iff x[b, 32w+j]==t (pos<MAXLEN)
__global__ void prep_x_kernel(const int* __restrict__ x,
                              unsigned int* __restrict__ bits) {
  int idx = blockIdx.x * blockDim.x + threadIdx.x;
  if (idx >= B_SZ * 32) return;
  int b = idx >> 5;
  int w = idx & 31;
  const int* xr = x + (size_t)b * MAXLEN + w * 32;
  int xv[32];
#pragma unroll
  for (int j = 0; j < 32; ++j) {
    int k = w * 32 + j;
    xv[j] = (k < MAXLEN) ? xr[j] : -1;
  }
#pragma unroll
  for (int t = 0; t < TSTEPS; ++t) {
    unsigned int m = 0;
#pragma unroll
    for (int j = 0; j < 32; ++j)
      m |= (xv[j] == t) ? (1u << j) : 0u;
    bits[((size_t)t * B_SZ + b) * 32 + w] = m;
  }
}

// ============================================================
// STEP ROLE: 16 recurrent K-iters (hi+lo) + gx add + LSTM cell epilogue.
// single-buffered LDS {A,Bh,Bl} 30 KB; gc 16.9 KB reuse. [R10-validated math]
// ============================================================
template <int LAYER>
__device__ void step_role(char* smraw, int sid, int step,
                          const unsigned short* __restrict__ Bhrec,   // [2,G4,512]
                          const unsigned short* __restrict__ Blrec,   // [2,G4,512]
                          const float* __restrict__ bias,             // [2,G4]
                          const unsigned short* __restrict__ h_in,    // [2,B,H]
                          unsigned short* __restrict__ h_out,
                          float* __restrict__ c_st,                   // [2,B,H]
                          unsigned short* __restrict__ seq_out,       // [T,B,2H] (L0)
                          float* __restrict__ zacc,                   // [B,2H]   (L1)
                          const float* __restrict__ emb_w,            // [21]     (L1)
                          const float* __restrict__ gxcur) {          // [2,B,G4]
  unsigned short* sA  = (unsigned short*)smraw;            // 128*40
  unsigned short* sBh = sA + BM * LDSKS;
  unsigned short* sBl = sBh + BN * LDSKS;
  float*          gc  = (float*)smraw;                     // epilogue reuse

  const int tid  = threadIdx.x;
  const int lane = tid & 63;
  const int wave = tid >> 6;
  const int wr   = wave >> 1;
  const int wc   = wave & 1;
  const int q    = lane >> 4;
  const int r16  = lane & 15;

  const int xcd  = sid & 7;
  const int slot = sid >> 3;
  const int nb   = xcd * 2 + (slot & 1);
  const int mb   = (slot >> 1) & 15;
  const int d    = slot >> 5;
  const int tcur = d ? (TSTEPS - 1 - step) : step;
  const int n0   = nb * BN;
  const int m0   = mb * BM;

  const unsigned short* Bh_mat = Bhrec + (size_t)d * G4 * H_SZ;
  const unsigned short* Bl_mat = Blrec + (size_t)d * G4 * H_SZ;
  const unsigned short* Ah     = h_in + (size_t)d * B_SZ * H_SZ;

  float bval[4];
#pragma unroll
  for (int nt = 0; nt < 4; ++nt)
    bval[nt] = bias[d * G4 + n0 + wc * 64 + nt * 16 + r16];

  f32x4 acc[2][4];
#pragma unroll
  for (int mt = 0; mt < 2; ++mt)
#pragma unroll
    for (int nt = 0; nt < 4; ++nt) {
      f32x4 z = {0.f, 0.f, 0.f, 0.f};
      acc[mt][nt] = z;
    }

  const int rstg = tid >> 2;
  const int ostg = (tid & 3) * 8;

  ushort8 pbh, pbl, pva;
  auto load_iter = [&](int kt) {
    const int k0 = kt * BKS;
    pbh = *(const ushort8*)(Bh_mat + (size_t)(n0 + rstg) * H_SZ + k0 + ostg);
    pbl = *(const ushort8*)(Bl_mat + (size_t)(n0 + rstg) * H_SZ + k0 + ostg);
    pva = *(const ushort8*)(Ah + (size_t)(m0 + rstg) * H_SZ + k0 + ostg);
  };

  load_iter(0);
  for (int kt = 0; kt < NITS; ++kt) {
    if (kt) __syncthreads();           // prev iter's MFMA LDS reads done
    *(ushort8*)(sA + rstg * LDSKS + ostg)  = pva;
    *(ushort8*)(sBh + rstg * LDSKS + ostg) = pbh;
    *(ushort8*)(sBl + rstg * LDSKS + ostg) = pbl;
    __syncthreads();
    if (kt + 1 < NITS) load_iter(kt + 1);

    bf16x8 af[2], bh[4];
#pragma unroll
    for (int mt = 0; mt < 2; ++mt)
      af[mt] = *(const bf16x8*)(sA + (wr * 32 + mt * 16 + r16) * LDSKS + q * 8);
#pragma unroll
    for (int nt = 0; nt < 4; ++nt)
      bh[nt] = *(const bf16x8*)(sBh + (wc * 64 + nt * 16 + r16) * LDSKS + q * 8);
#pragma unroll
    for (int mt = 0; mt < 2; ++mt)
#pragma unroll
      for (int nt = 0; nt < 4; ++nt)
        acc[mt][nt] = __builtin_amdgcn_mfma_f32_16x16x32_bf16(af[mt], bh[nt], acc[mt][nt], 0, 0, 0);
    bf16x8 bl[4];
#pragma unroll
    for (int nt = 0; nt < 4; ++nt)
      bl[nt] = *(const bf16x8*)(sBl + (wc * 64 + nt * 16 + r16) * LDSKS + q * 8);
#pragma unroll
    for (int mt = 0; mt < 2; ++mt)
#pragma unroll
      for (int nt = 0; nt < 4; ++nt)
        acc[mt][nt] = __builtin_amdgcn_mfma_f32_16x16x32_bf16(af[mt], bl[nt], acc[mt][nt], 0, 0, 0);
  }
  __syncthreads();

  // ---- epilogue: 4 chunks of 32 gate-cols through 128x33 gc ----
  // C/D layout: col=lane&15, row=(lane>>4)*4+reg  [m89/m91 verified]
  const int jbase = nb * 32;
  const float ew = (LAYER == 1) ? emb_w[tcur] : 0.f;

#pragma unroll
  for (int cc2 = 0; cc2 < 4; ++cc2) {
    if (wc == (cc2 >> 1)) {
      const int ntb = (cc2 & 1) * 2;
#pragma unroll
      for (int nti = 0; nti < 2; ++nti) {
        const int nt = ntb + nti;
#pragma unroll
        for (int mt = 0; mt < 2; ++mt)
#pragma unroll
          for (int r = 0; r < 4; ++r) {
            int ml = wr * 32 + mt * 16 + q * 4 + r;
            int nl = nti * 16 + r16;
            gc[ml * GPAD + nl] = acc[mt][nt][r] + bval[nt];
          }
      }
    }
    __syncthreads();

#pragma unroll
    for (int it = 0; it < 2; ++it) {
      int cell = it * 512 + tid;
      int rl = cell >> 3;
      int jq = cell & 7;
      int b = m0 + rl;
      int j = jbase + cc2 * 8 + jq;
      float4 g = *(const float4*)(&gc[rl * GPAD + jq * 4]);
      const float4 gx = *(const float4*)(gxcur + ((size_t)d * B_SZ + b) * G4 + (size_t)j * 4);
      g.x += gx.x; g.y += gx.y; g.z += gx.z; g.w += gx.w;
      float si = sigmoidf_(g.x);
      float sf = sigmoidf_(g.y);
      float tg = tanhf_(g.z);
      float so = sigmoidf_(g.w);
      size_t cidx = ((size_t)d * B_SZ + b) * H_SZ + j;
      float cn = sf * c_st[cidx] + si * tg;
      float hv = so * tanhf_(cn);
      c_st[cidx] = cn;
      h_out[cidx] = f2bf(hv);
      if (LAYER == 0) {
        seq_out[((size_t)tcur * B_SZ + b) * (2 * H_SZ) + d * H_SZ + j] = f2bf(hv);
      } else {
        zacc[(size_t)b * (2 * H_SZ) + d * H_SZ + j] += ew * hv;
      }
    }
    __syncthreads();
  }
}

// ============================================================
// GX ROLE: dense input-projection GEMM for step gx_step (runs in the shadow of
// the step chain). BK=64, 16 iters. Writes gx[d][b][p] f32 (sole writer).
// L0: A = one-hot from xbits; L1: A = seq0[t].
// ============================================================
template <int LAYER>
__device__ void gx_role(char* smraw, int gid, int gx_step,
                        const unsigned int* __restrict__ xbits,     // [21,B,32]
                        const unsigned short* __restrict__ seq0,    // [T,B,2H]
                        const unsigned short* __restrict__ Bin,     // [2,G4,KIN]
                        float* __restrict__ gxnext) {               // [2,B,G4]
  if (gx_step >= TSTEPS) return;

  unsigned short* sA = (unsigned short*)smraw;            // 128*72
  unsigned short* sB = sA + BM * LDSKG;

  const int tid  = threadIdx.x;
  const int lane = tid & 63;
  const int wave = tid >> 6;
  const int wr   = wave >> 1;
  const int wc   = wave & 1;
  const int q    = lane >> 4;
  const int r16  = lane & 15;

  const int xcd  = gid & 7;
  const int slot = gid >> 3;
  const int nb   = xcd * 2 + (slot & 1);
  const int mb   = (slot >> 1) & 15;
  const int d    = slot >> 5;
  const int tg   = d ? (TSTEPS - 1 - gx_step) : gx_step;
  const int n0   = nb * BN;
  const int m0   = mb * BM;

  const unsigned short* Bmat = Bin + (size_t)d * G4 * KIN;
  const unsigned char*  xrow = (const unsigned char*)xbits + ((size_t)tg * B_SZ) * (KIN / 8);
  const unsigned short* Asrc = seq0 + (size_t)tg * B_SZ * (2 * H_SZ);

  f32x4 acc[2][4];
#pragma unroll
  for (int mt = 0; mt < 2; ++mt)
#pragma unroll
    for (int nt = 0; nt < 4; ++nt) {
      f32x4 z = {0.f, 0.f, 0.f, 0.f};
      acc[mt][nt] = z;
    }

  // staging: tiles 128x64 = 1024 chunks of 8 elems; 2 per thread
  const int c0 = tid, c1 = tid + 512;
  const int r0 = c0 >> 3, r1 = c1 >> 3;
  const int o0 = (c0 & 7) * 8, o1 = (c1 & 7) * 8;

  ushort8 pb0, pb1, pa0, pa1;
  unsigned int bv0, bv1;
  auto load_iter = [&](int kt) {
    const int k0 = kt * BKG;
    pb0 = *(const ushort8*)(Bmat + (size_t)(n0 + r0) * KIN + k0 + o0);
    pb1 = *(const ushort8*)(Bmat + (size_t)(n0 + r1) * KIN + k0 + o1);
    if (LAYER == 0) {
      bv0 = xrow[(size_t)(m0 + r0) * (KIN / 8) + (k0 + o0) / 8];
      bv1 = xrow[(size_t)(m0 + r1) * (KIN / 8) + (k0 + o1) / 8];
    } else {
      pa0 = *(const ushort8*)(Asrc + (size_t)(m0 + r0) * (2 * H_SZ) + k0 + o0);
      pa1 = *(const ushort8*)(Asrc + (size_t)(m0 + r1) * (2 * H_SZ) + k0 + o1);
    }
  };

  load_iter(0);
  for (int kt = 0; kt < NITG; ++kt) {
    if (kt) __syncthreads();
    if (LAYER == 0) {
      unsigned int pk0[4], pk1[4];
#pragma unroll
      for (int e = 0; e < 4; ++e) {
        pk0[e] = (((bv0 >> (2 * e)) & 1u) ? 0x3F80u : 0u)
               | (((bv0 >> (2 * e + 1)) & 1u) ? 0x3F800000u : 0u);
        pk1[e] = (((bv1 >> (2 * e)) & 1u) ? 0x3F80u : 0u)
               | (((bv1 >> (2 * e + 1)) & 1u) ? 0x3F800000u : 0u);
      }
      *(uint4*)(sA + r0 * LDSKG + o0) = make_uint4(pk0[0], pk0[1], pk0[2], pk0[3]);
      *(uint4*)(sA + r1 * LDSKG + o1) = make_uint4(pk1[0], pk1[1], pk1[2], pk1[3]);
    } else {
      *(ushort8*)(sA + r0 * LDSKG + o0) = pa0;
      *(ushort8*)(sA + r1 * LDSKG + o1) = pa1;
    }
    *(ushort8*)(sB + r0 * LDSKG + o0) = pb0;
    *(ushort8*)(sB + r1 * LDSKG + o1) = pb1;
    __syncthreads();
    if (kt + 1 < NITG) load_iter(kt + 1);

#pragma unroll
    for (int kh = 0; kh < 2; ++kh) {
      bf16x8 af[2], bh[4];
#pragma unroll
      for (int mt = 0; mt < 2; ++mt)
        af[mt] = *(const bf16x8*)(sA + (wr * 32 + mt * 16 + r16) * LDSKG + kh * 32 + q * 8);
#pragma unroll
      for (int nt = 0; nt < 4; ++nt)
        bh[nt] = *(const bf16x8*)(sB + (wc * 64 + nt * 16 + r16) * LDSKG + kh * 32 + q * 8);
#pragma unroll
      for (int mt = 0; mt < 2; ++mt)
#pragma unroll
        for (int nt = 0; nt < 4; ++nt)
          acc[mt][nt] = __builtin_amdgcn_mfma_f32_16x16x32_bf16(af[mt], bh[nt], acc[mt][nt], 0, 0, 0);
    }
  }

  // write gx (C/D layout: col=lane&15, row=quad*4+reg)
#pragma unroll
  for (int mt = 0; mt < 2; ++mt)
#pragma unroll
    for (int nt = 0; nt < 4; ++nt)
#pragma unroll
      for (int r = 0; r < 4; ++r) {
        int row = m0 + wr * 32 + mt * 16 + q * 4 + r;
        int col = n0 + wc * 64 + nt * 16 + r16;
        gxnext[((size_t)d * B_SZ + row) * G4 + col] = acc[mt][nt][r];
      }
}

// ============================================================ fused launcher
template <int LAYER>
__global__ __launch_bounds__(512, 8)
void fused_kernel(const unsigned int* __restrict__ xbits,
                  const unsigned short* __restrict__ seq0,
                  const unsigned short* __restrict__ Bin,
                  const unsigned short* __restrict__ Bhrec,
                  const unsigned short* __restrict__ Blrec,
                  const float* __restrict__ bias,
                  const unsigned short* __restrict__ h_in,
                  unsigned short* __restrict__ h_out,
                  float* __restrict__ c_st,
                  unsigned short* __restrict__ seq_out,
                  float* __restrict__ zacc,
                  const float* __restrict__ emb_w,
                  const float* __restrict__ gxcur,
                  float* __restrict__ gxnext,
                  int step, int gx_step) {
  extern __shared__ char smraw[];
  const int bid = blockIdx.x;
  if ((bid & 1) == 0) {
    step_role<LAYER>(smraw, bid >> 1, step, Bhrec, Blrec, bias, h_in, h_out,
                     c_st, seq_out, zacc, emb_w, gxcur);
  } else {
    gx_role<LAYER>(smraw, bid >> 1, gx_step, xbits, seq0, Bin, gxnext);
  }
}

template <int LAYER>
__global__ __launch_bounds__(512, 8)
void gx_only_kernel(const unsigned int* __restrict__ xbits,
                    const unsigned short* __restrict__ seq0,
                    const unsigned short* __restrict__ Bin,
                    float* __restrict__ gxnext, int gx_step) {
  extern __shared__ char smraw[];
  gx_role<LAYER>(smraw, blockIdx.x, gx_step, xbits, seq0, Bin, gxnext);
}

// ============================================================ final
__global__ __launch_bounds__(256)
void final_kernel(const float* __restrict__ zacc,
                  const float* __restrict__ emb_b,
                  const float* __restrict__ fc_w,
                  const float* __restrict__ fc_b,
                  float* __restrict__ out) {
  const int b = blockIdx.x;
  const int tid = threadIdx.x;
  const int c0 = tid * 4;

  const float zb = emb_b[0];
  const float4 z4 = *(const float4*)(zacc + (size_t)b * (2 * H_SZ) + c0);
  float z0 = z4.x + zb, z1 = z4.y + zb, z2 = z4.z + zb, z3 = z4.w + zb;

  float part[NCLS];
#pragma unroll
  for (int nc = 0; nc < NCLS; ++nc) {
    const float4 f = *(const float4*)(fc_w + (size_t)nc * (2 * H_SZ) + c0);
    part[nc] = z0 * f.x + z1 * f.y + z2 * f.z + z3 * f.w;
  }
#pragma unroll
  for (int nc = 0; nc < NCLS; ++nc)
#pragma unroll
    for (int off2 = 32; off2 > 0; off2 >>= 1)
      part[nc] += __shfl_down(part[nc], off2);

  __shared__ float red[4][NCLS];
  if ((tid & 63) == 0) {
#pragma unroll
    for (int nc = 0; nc < NCLS; ++nc) red[tid >> 6][nc] = part[nc];
  }
  __syncthreads();
  if (tid < NCLS) {
    float s = red[0][tid] + red[1][tid] + red[2][tid] + red[3][tid] + fc_b[tid];
    out[b * NCLS + tid] = s;
  }
}

// ============================================================
extern "C" void kernel_launch(void* const* d_in, const int* in_sizes, int n_in,
                              void* d_out, int out_size, void* d_ws, size_t ws_size,
                              hipStream_t stream) {
  (void)in_sizes; (void)n_in; (void)out_size; (void)ws_size;

  const int*   x     = (const int*)d_in[0];
  const float* w_ih0 = (const float*)d_in[1];
  const float* w_hh0 = (const float*)d_in[2];
  const float* b_ih0 = (const float*)d_in[3];
  const float* b_hh0 = (const float*)d_in[4];
  const float* w_ih1 = (const float*)d_in[5];
  const float* w_hh1 = (const float*)d_in[6];
  const float* b_ih1 = (const float*)d_in[7];
  const float* b_hh1 = (const float*)d_in[8];
  const float* emb_w = (const float*)d_in[9];
  const float* emb_b = (const float*)d_in[10];
  const float* fc_w  = (const float*)d_in[11];
  const float* fc_b  = (const float*)d_in[12];

  // -------- workspace (~211 MB) --------
  char* ws = (char*)d_ws;
  size_t off = 0;
  auto alloc = [&](size_t bytes) -> void* {
    void* p = ws + off;
    off += (bytes + 255) & ~(size_t)255;
    return p;
  };
  const size_t bin_b  = (size_t)2 * G4 * KIN * 2;               // 8.39 MB
  const size_t brec_b = (size_t)2 * G4 * H_SZ * 2;              // 4.19 MB
  const size_t xb_b   = (size_t)TSTEPS * B_SZ * 32 * 4;         // 5.50 MB
  const size_t h_b    = (size_t)2 * B_SZ * H_SZ * 2;            // 4.19 MB
  const size_t c_b    = (size_t)2 * B_SZ * H_SZ * 4;            // 8.39 MB
  const size_t gx_b   = (size_t)2 * B_SZ * G4 * 4;              // 33.55 MB
  const size_t seq_b  = (size_t)TSTEPS * B_SZ * (2 * H_SZ) * 2; // 88.08 MB
  const size_t z_b    = (size_t)B_SZ * (2 * H_SZ) * 4;          // 8.39 MB

  unsigned short* Bin0  = (unsigned short*)alloc(bin_b);   // L0-only; zacc aliases
  unsigned short* Bin1  = (unsigned short*)alloc(bin_b);
  unsigned short* Bh0   = (unsigned short*)alloc(brec_b);
  unsigned short* Bl0   = (unsigned short*)alloc(brec_b);
  unsigned short* Bh1   = (unsigned short*)alloc(brec_b);
  unsigned short* Bl1   = (unsigned short*)alloc(brec_b);
  float*          bias0 = (float*)alloc((size_t)2 * G4 * 4);
  float*          bias1 = (float*)alloc((size_t)2 * G4 * 4);
  unsigned int*   xbits = (unsigned int*)alloc(xb_b);
  unsigned short* hA    = (unsigned short*)alloc(h_b);
  unsigned short* hB    = (unsigned short*)alloc(h_b);
  float*          cst   = (float*)alloc(c_b);
  float*          gxA   = (float*)alloc(gx_b);
  float*          gxB   = (float*)alloc(gx_b);
  unsigned short* seq0  = (unsigned short*)alloc(seq_b);
  float*          zacc  = (float*)Bin0;   // Bin0 (8.39 MB) dead after layer 0; z_b == bin_b

  // -------- prep --------
  {
    size_t ti = (size_t)2 * G4 * KIN;
    prep_in0_kernel<<<(int)((ti + 255) / 256), 256, 0, stream>>>(w_ih0, Bin0);
    prep_in1_kernel<<<(int)((ti + 255) / 256), 256, 0, stream>>>(w_ih1, Bin1);
    size_t tr = (size_t)2 * G4 * H_SZ;
    prep_rec_kernel<<<(int)((tr + 255) / 256), 256, 0, stream>>>(w_hh0, Bh0, Bl0);
    prep_rec_kernel<<<(int)((tr + 255) / 256), 256, 0, stream>>>(w_hh1, Bh1, Bl1);
    prep_b_kernel<<<16, 256, 0, stream>>>(b_ih0, b_hh0, b_ih1, b_hh1, bias0, bias1);
    prep_x_kernel<<<(B_SZ * 32 + 255) / 256, 256, 0, stream>>>(x, xbits);
  }

  // -------- layer 0 --------
  hipMemsetAsync(hA, 0, h_b, stream);
  hipMemsetAsync(cst, 0, c_b, stream);
  gx_only_kernel<0><<<512, 512, SMEM_BYTES, stream>>>(xbits, nullptr, Bin0, gxA, 0);
  for (int s = 0; s < TSTEPS; ++s) {
    const unsigned short* hin  = (s & 1) ? hB : hA;
    unsigned short*       hout = (s & 1) ? hA : hB;
    float* cur = (s & 1) ? gxB : gxA;
    float* nxt = (s & 1) ? gxA : gxB;
    fused_kernel<0><<<1024, 512, SMEM_BYTES, stream>>>(
        xbits, nullptr, Bin0, Bh0, Bl0, bias0, hin, hout, cst,
        seq0, nullptr, nullptr, cur, nxt, s, s + 1);
  }

  // -------- layer 1 --------
  hipMemsetAsync(hA, 0, h_b, stream);
  hipMemsetAsync(cst, 0, c_b, stream);
  hipMemsetAsync(zacc, 0, z_b, stream);
  gx_only_kernel<1><<<512, 512, SMEM_BYTES, stream>>>(nullptr, seq0, Bin1, gxA, 0);
  for (int s = 0; s < TSTEPS; ++s) {
    const unsigned short* hin  = (s & 1) ? hB : hA;
    unsigned short*       hout = (s & 1) ? hA : hB;
    float* cur = (s & 1) ? gxB : gxA;
    float* nxt = (s & 1) ? gxA : gxB;
    fused_kernel<1><<<1024, 512, SMEM_BYTES, stream>>>(
        nullptr, seq0, Bin1, Bh1, Bl1, bias1, hin, hout, cst,
        nullptr, zacc, emb_w, cur, nxt, s, s + 1);
  }

  // -------- fc --------
  final_kernel<<<B_SZ, 256, 0, stream>>>(zacc, emb_b, fc_w, fc_b, (float*)d_out);
}